// Round 12
// baseline (251.115 us; speedup 1.0000x reference)
//
#include <hip/hip_runtime.h>

// ---------- bf16 helpers (bit-level, RNE) ----------
__device__ __forceinline__ float bf2f(unsigned short u) {
    union { unsigned int i; float f; } v;
    v.i = ((unsigned int)u) << 16;
    return v.f;
}
__device__ __forceinline__ unsigned short f2bf(float f) {
    union { float f; unsigned int u; } v;
    v.f = f;
    unsigned int u = v.u;
    u += 0x7FFFu + ((u >> 16) & 1u);   // round-to-nearest-even
    return (unsigned short)(u >> 16);
}
__device__ __forceinline__ float loadElem(const void* p, size_t i, int isb) {
    return isb ? bf2f(((const unsigned short*)p)[i]) : ((const float*)p)[i];
}
__device__ __forceinline__ void fma4(float4& a, float s, const float4& w) {
    a.x += s * w.x; a.y += s * w.y; a.z += s * w.z; a.w += s * w.w;
}
__device__ __forceinline__ float bflo(unsigned int u) {
    union { unsigned int i; float f; } v; v.i = u << 16; return v.f;
}
__device__ __forceinline__ float bfhi(unsigned int u) {
    union { unsigned int i; float f; } v; v.i = u & 0xFFFF0000u; return v.f;
}

#define CHUNK 1024            // edges per partition block (4.6 blocks/CU)
#define BSHIFT 7              // 128 nodes per sort bucket (782 buckets @ N=100k)
#define BN (1 << BSHIFT)

// ---------- runtime dtype detection (proven r3-r11) ----------
__global__ void k_detect(const int* __restrict__ ei, int newords,
                         const unsigned int* __restrict__ xw, int nxw,
                         int* __restrict__ flags) {
    __shared__ int aOr;
    __shared__ int plaus;
    if (threadIdx.x == 0) { aOr = 0; plaus = 0; }
    __syncthreads();
    int v = 0;
    for (int i = 1 + 2 * (int)threadIdx.x; i < newords; i += 512) v |= ei[i];
    int pl = 0;
    for (int i = threadIdx.x; i < nxw; i += 256) {
        unsigned short lo = (unsigned short)(xw[i] & 0xFFFFu);
        float a = fabsf(bf2f(lo));
        if (a > 1e-5f && a < 100.0f) pl++;
    }
    atomicOr(&aOr, v);
    atomicAdd(&plaus, pl);
    __syncthreads();
    if (threadIdx.x == 0) {
        flags[0] = (aOr == 0) ? 1 : 0;
        flags[1] = (2 * plaus >= nxw) ? 1 : 0;
    }
}

// ---------- cast x -> bf16 (copy-through if already bf16) ----------
__global__ void k_cast(const void* __restrict__ x, unsigned short* __restrict__ xb,
                       int n8, const int* __restrict__ flags) {
    int i = blockIdx.x * blockDim.x + threadIdx.x;
    if (i >= n8) return;
    if (flags[1]) {
        ((uint4*)xb)[i] = ((const uint4*)x)[i];
    } else {
        const float4* xf = (const float4*)x;
        float4 a = xf[2 * i], b = xf[2 * i + 1];
        ushort4 lo = { f2bf(a.x), f2bf(a.y), f2bf(a.z), f2bf(a.w) };
        ushort4 hi = { f2bf(b.x), f2bf(b.y), f2bf(b.z), f2bf(b.w) };
        ((ushort4*)xb)[2 * i] = lo;
        ((ushort4*)xb)[2 * i + 1] = hi;
    }
}

// ---------- CSR build: counting sort with parallel scans (r7/r9 structure) ----------
__global__ __launch_bounds__(256) void k_bcount(
        const int* __restrict__ ei, const int* __restrict__ flags,
        int* __restrict__ blockHist, int E, int NBUK, int nblk) {
    __shared__ int hist[1024];
    int t = threadIdx.x;
    for (int i = t; i < NBUK; i += 256) hist[i] = 0;
    __syncthreads();
    int q = flags[0];
    int e0 = blockIdx.x * CHUNK, e1 = min(E, e0 + CHUNK);
    for (int e = e0 + t; e < e1; e += 256) {
        int dst = ei[((size_t)(E + e)) << q];
        atomicAdd(&hist[dst >> BSHIFT], 1);
    }
    __syncthreads();
    for (int i = t; i < NBUK; i += 256)
        blockHist[(size_t)i * nblk + blockIdx.x] = hist[i];
}

__global__ __launch_bounds__(256) void k_rowscan(
        int* __restrict__ blockHist, int* __restrict__ bukTot, int nblk) {
    __shared__ int sh[256];
    int t = threadIdx.x;
    int* row = blockHist + (size_t)blockIdx.x * nblk;
    int carry = 0;
    for (int base = 0; base < nblk; base += 256) {
        int i = base + t;
        int v = (i < nblk) ? row[i] : 0;
        sh[t] = v;
        __syncthreads();
        for (int off = 1; off < 256; off <<= 1) {
            int u = (t >= off) ? sh[t - off] : 0;
            __syncthreads();
            sh[t] += u;
            __syncthreads();
        }
        if (i < nblk) row[i] = carry + sh[t] - v;
        int tot = sh[255];
        __syncthreads();
        carry += tot;
    }
    if (t == 0) bukTot[blockIdx.x] = carry;
}

// tiled single-block exclusive scan (NBUK may exceed 1024)
__global__ __launch_bounds__(1024) void k_toto(
        const int* __restrict__ bukTot, int* __restrict__ bukOff,
        int* __restrict__ rowptr, int NBUK, int E, int N) {
    __shared__ int sh[1024];
    int t = threadIdx.x;
    int carry = 0;
    for (int base = 0; base < NBUK; base += 1024) {
        int i = base + t;
        int v = (i < NBUK) ? bukTot[i] : 0;
        sh[t] = v;
        __syncthreads();
        for (int off = 1; off < 1024; off <<= 1) {
            int u = (t >= off) ? sh[t - off] : 0;
            __syncthreads();
            sh[t] += u;
            __syncthreads();
        }
        if (i < NBUK) bukOff[i] = carry + sh[t] - v;
        int tot = sh[1023];
        __syncthreads();
        carry += tot;
    }
    if (t == 0) { bukOff[NBUK] = E; rowptr[N] = E; }
}

__global__ __launch_bounds__(256) void k_part(
        const int* __restrict__ ei, const int* __restrict__ flags,
        const int* __restrict__ blockHist, const int* __restrict__ bukOff,
        unsigned int* __restrict__ recs, int E, int NBUK, int nblk) {
    __shared__ int cur[1024];
    int t = threadIdx.x;
    for (int i = t; i < NBUK; i += 256)
        cur[i] = blockHist[(size_t)i * nblk + blockIdx.x] + bukOff[i];
    __syncthreads();
    int q = flags[0];
    int e0 = blockIdx.x * CHUNK, e1 = min(E, e0 + CHUNK);
    for (int e = e0 + t; e < e1; e += 256) {
        int dst = ei[((size_t)(E + e)) << q];
        int src = ei[((size_t)e) << q];
        int pos = atomicAdd(&cur[dst >> BSHIFT], 1);
        recs[pos] = ((unsigned int)src << BSHIFT) | (unsigned int)(dst & (BN - 1));
    }
}

__global__ __launch_bounds__(256) void k_csr(
        const unsigned int* __restrict__ recs, const int* __restrict__ bukOff,
        int* __restrict__ rowptr, int* __restrict__ esorted, int N) {
    __shared__ int degLoc[BN];
    __shared__ int offLoc[BN];
    __shared__ int wcur[BN];
    int t = threadIdx.x;
    int node0 = blockIdx.x << BSHIFT;
    int r0 = bukOff[blockIdx.x], r1 = bukOff[blockIdx.x + 1];
    if (t < BN) degLoc[t] = 0;
    __syncthreads();
    for (int i = r0 + t; i < r1; i += 256)
        atomicAdd(&degLoc[recs[i] & (BN - 1)], 1);
    __syncthreads();
    int v = (t < BN) ? degLoc[t] : 0;
    if (t < BN) offLoc[t] = v;
    __syncthreads();
    for (int off = 1; off < BN; off <<= 1) {
        int u = (t >= off && t < BN) ? offLoc[t - off] : 0;
        __syncthreads();
        if (t < BN) offLoc[t] += u;
        __syncthreads();
    }
    if (t < BN) {
        int excl = offLoc[t] - v;
        int node = node0 + t;
        if (node < N) rowptr[node] = r0 + excl;
        wcur[t] = r0 + excl;
    }
    __syncthreads();
    for (int i = r0 + t; i < r1; i += 256) {
        unsigned int rec = recs[i];
        int pos = atomicAdd(&wcur[rec & (BN - 1)], 1);
        esorted[pos] = (int)(rec >> BSHIFT);
    }
}

// ---------- fused layer 1 (r11 verbatim — proven 68 us) ----------
template<int CHOUT, bool RELU, bool FINAL>
__global__ __launch_bounds__(256) void k_fused(
        const unsigned short* __restrict__ feat,
        const int* __restrict__ rowptr,
        const int* __restrict__ esorted,
        const void* __restrict__ Wl,
        const void* __restrict__ Wr,
        const void* __restrict__ bias,
        void* __restrict__ outp,
        int N, const int* __restrict__ flags) {
    constexpr int SA = 68;
    __shared__ float amBuf[64 * SA];
    __shared__ unsigned short wS16[64 * CHOUT];
    __shared__ float Bs[CHOUT];

    int t = threadIdx.x;
    int isb = flags[1];
    int node0 = blockIdx.x << 6;

    if (isb) {
        for (int i = t; i < (64 * CHOUT) / 8; i += 256)
            ((uint4*)wS16)[i] = ((const uint4*)Wl)[i];
    } else {
        for (int i = t; i < 64 * CHOUT; i += 256)
            wS16[i] = f2bf(((const float*)Wl)[i]);
    }
    if (t < CHOUT) Bs[t] = loadElem(bias, t, isb);

    {
        int g = t >> 4, l = t & 15;
        int gb = (t & 63) & ~15;
#pragma unroll
        for (int jj = 0; jj < 4; ++jj) {
            int nl = g + 16 * jj;
            int node = node0 + nl;
            float ax = 0.f, ay = 0.f, az = 0.f, aw = 0.f;
            float inv = 0.f;
            if (node < N) {
                int beg = rowptr[node], end = rowptr[node + 1];
                int d = end - beg;
                if (d > 0) {
                    inv = 1.0f / (float)d;
                    for (int bs = beg; bs < end; bs += 16) {
                        int cnt = min(end - bs, 16);
                        int idx = esorted[min(bs + l, end - 1)];
                        int dd = 0;
                        for (; dd + 4 <= cnt; dd += 4) {
                            int s0 = __shfl(idx, gb + dd + 0, 64);
                            int s1 = __shfl(idx, gb + dd + 1, 64);
                            int s2 = __shfl(idx, gb + dd + 2, 64);
                            int s3 = __shfl(idx, gb + dd + 3, 64);
                            ushort4 u0 = *(const ushort4*)(feat + (size_t)s0 * 64 + 4 * l);
                            ushort4 u1 = *(const ushort4*)(feat + (size_t)s1 * 64 + 4 * l);
                            ushort4 u2 = *(const ushort4*)(feat + (size_t)s2 * 64 + 4 * l);
                            ushort4 u3 = *(const ushort4*)(feat + (size_t)s3 * 64 + 4 * l);
                            ax += bf2f(u0.x) + bf2f(u1.x) + bf2f(u2.x) + bf2f(u3.x);
                            ay += bf2f(u0.y) + bf2f(u1.y) + bf2f(u2.y) + bf2f(u3.y);
                            az += bf2f(u0.z) + bf2f(u1.z) + bf2f(u2.z) + bf2f(u3.z);
                            aw += bf2f(u0.w) + bf2f(u1.w) + bf2f(u2.w) + bf2f(u3.w);
                        }
                        for (; dd < cnt; ++dd) {
                            int s = __shfl(idx, gb + dd, 64);
                            ushort4 u = *(const ushort4*)(feat + (size_t)s * 64 + 4 * l);
                            ax += bf2f(u.x); ay += bf2f(u.y);
                            az += bf2f(u.z); aw += bf2f(u.w);
                        }
                    }
                }
            }
            *(float4*)&amBuf[nl * SA + 4 * l] =
                make_float4(ax * inv, ay * inv, az * inv, aw * inv);
        }
    }
    __syncthreads();

    constexpr int CQ = CHOUT / 4;
    constexpr int NPT = CHOUT / 16;
    int cq = t % CQ, nq = t / CQ;
    float4 acc[NPT];
#pragma unroll
    for (int j = 0; j < NPT; ++j) acc[j] = make_float4(0.f, 0.f, 0.f, 0.f);

#pragma unroll 8
    for (int k = 0; k < 64; ++k) {
        uint2 wu = *(const uint2*)&wS16[k * CHOUT + 4 * cq];
        float4 w = make_float4(bflo(wu.x), bfhi(wu.x), bflo(wu.y), bfhi(wu.y));
#pragma unroll
        for (int j = 0; j < NPT; ++j)
            fma4(acc[j], amBuf[(nq * NPT + j) * SA + k], w);
    }
    __syncthreads();

    for (int i = t; i < 64 * 8; i += 256) {
        int nl = i >> 3, k0 = (i & 7) << 3;
        int gn = node0 + nl;
        float v[8];
        if (gn < N) {
            uint4 u = *(const uint4*)(feat + (size_t)gn * 64 + k0);
            v[0] = bflo(u.x); v[1] = bfhi(u.x);
            v[2] = bflo(u.y); v[3] = bfhi(u.y);
            v[4] = bflo(u.z); v[5] = bfhi(u.z);
            v[6] = bflo(u.w); v[7] = bfhi(u.w);
        } else {
#pragma unroll
            for (int j = 0; j < 8; ++j) v[j] = 0.f;
        }
#pragma unroll
        for (int j = 0; j < 8; ++j) amBuf[nl * SA + k0 + j] = v[j];
    }
    if (isb) {
        for (int i = t; i < (64 * CHOUT) / 8; i += 256)
            ((uint4*)wS16)[i] = ((const uint4*)Wr)[i];
    } else {
        for (int i = t; i < 64 * CHOUT; i += 256)
            wS16[i] = f2bf(((const float*)Wr)[i]);
    }
    __syncthreads();

#pragma unroll 8
    for (int k = 0; k < 64; ++k) {
        uint2 wu = *(const uint2*)&wS16[k * CHOUT + 4 * cq];
        float4 w = make_float4(bflo(wu.x), bfhi(wu.x), bflo(wu.y), bfhi(wu.y));
#pragma unroll
        for (int j = 0; j < NPT; ++j)
            fma4(acc[j], amBuf[(nq * NPT + j) * SA + k], w);
    }

    float4 bv = *(const float4*)&Bs[4 * cq];
#pragma unroll
    for (int j = 0; j < NPT; ++j) {
        int nl = nq * NPT + j;
        int node = node0 + nl;
        if (node >= N) continue;
        float4 r = acc[j];
        r.x += bv.x; r.y += bv.y; r.z += bv.z; r.w += bv.w;
        if (RELU) {
            r.x = fmaxf(r.x, 0.f); r.y = fmaxf(r.y, 0.f);
            r.z = fmaxf(r.z, 0.f); r.w = fmaxf(r.w, 0.f);
        }
        if (FINAL && !isb) {
            *(float4*)((float*)outp + (size_t)node * CHOUT + 4 * cq) = r;
        } else {
            ushort4 o = { f2bf(r.x), f2bf(r.y), f2bf(r.z), f2bf(r.w) };
            *(ushort4*)((unsigned short*)outp + (size_t)node * CHOUT + 4 * cq) = o;
        }
    }
}

// ---------- dense GEMM: y2 = h @ W2l, [N,64]x[64,32] -> bf16 [N,32] ----------
// 128-node tile, 256 threads, thread = 4 nodes x 4 ch (r5-proven shape)
__global__ __launch_bounds__(256) void k_gemm32(
        const unsigned short* __restrict__ A,      // [N,64] bf16 (h)
        const void* __restrict__ W,                // [64,32]
        unsigned short* __restrict__ D,            // [N,32] bf16
        int N, const int* __restrict__ flags) {
    constexpr int S = 130;
    __shared__ float As[64 * S];
    __shared__ unsigned short wS16[64 * 32];

    int t = threadIdx.x;
    int isb = flags[1];
    if (isb) {
        for (int i = t; i < (64 * 32) / 8; i += 256)
            ((uint4*)wS16)[i] = ((const uint4*)W)[i];
    } else {
        for (int i = t; i < 64 * 32; i += 256)
            wS16[i] = f2bf(((const float*)W)[i]);
    }
    int nodeBase = blockIdx.x * 128;
    for (int i = t; i < 128 * 8; i += 256) {
        int node = i >> 3, k0 = (i & 7) << 3;
        int gn = nodeBase + node;
        float v[8];
        if (gn < N) {
            uint4 u = *(const uint4*)(A + (size_t)gn * 64 + k0);
            v[0] = bflo(u.x); v[1] = bfhi(u.x);
            v[2] = bflo(u.y); v[3] = bfhi(u.y);
            v[4] = bflo(u.z); v[5] = bfhi(u.z);
            v[6] = bflo(u.w); v[7] = bfhi(u.w);
        } else {
#pragma unroll
            for (int j = 0; j < 8; ++j) v[j] = 0.f;
        }
#pragma unroll
        for (int j = 0; j < 8; ++j) As[(k0 + j) * S + node] = v[j];
    }
    __syncthreads();

    int cq = t % 8, nq = t / 8;                    // 4 nodes each
    float4 acc[4];
    acc[0] = acc[1] = acc[2] = acc[3] = make_float4(0.f, 0.f, 0.f, 0.f);

#pragma unroll 8
    for (int k = 0; k < 64; ++k) {
        uint2 wu = *(const uint2*)&wS16[k * 32 + 4 * cq];
        float4 w = make_float4(bflo(wu.x), bfhi(wu.x), bflo(wu.y), bfhi(wu.y));
        const float* ar = &As[k * S + 4 * nq];
        float2 a01 = *(const float2*)ar;
        float2 a23 = *(const float2*)(ar + 2);
        fma4(acc[0], a01.x, w);
        fma4(acc[1], a01.y, w);
        fma4(acc[2], a23.x, w);
        fma4(acc[3], a23.y, w);
    }

#pragma unroll
    for (int i = 0; i < 4; ++i) {
        int node = nodeBase + 4 * nq + i;
        if (node >= N) continue;
        float4 r = acc[i];
        ushort4 o = { f2bf(r.x), f2bf(r.y), f2bf(r.z), f2bf(r.w) };
        *(ushort4*)(D + (size_t)node * 32 + 4 * cq) = o;
    }
}

// ---------- fused layer 2: gather mean(y2) (64B rows) + h@W2r + bias ----------
// 64-node tile, 256 threads. Gather: 8-lane groups, 4-deep ILP. Single GEMM.
__global__ __launch_bounds__(256) void k_fused2(
        const unsigned short* __restrict__ y2,     // [N,32] bf16
        const unsigned short* __restrict__ h,      // [N,64] bf16
        const int* __restrict__ rowptr,
        const int* __restrict__ esorted,
        const void* __restrict__ Wr,               // [64,32]
        const void* __restrict__ bias,             // [32]
        void* __restrict__ outp,                   // [N,32]
        int N, const int* __restrict__ flags) {
    constexpr int SAM = 36;                        // f32 stride (16B-aligned float4)
    constexpr int SH = 68;                         // ushort stride (8B-aligned)
    __shared__ float amB[64 * SAM];
    __shared__ unsigned short hS16[64 * SH];
    __shared__ unsigned short wS16[64 * 32];
    __shared__ float Bs[32];

    int t = threadIdx.x;
    int isb = flags[1];
    int node0 = blockIdx.x << 6;

    if (isb) {
        for (int i = t; i < (64 * 32) / 8; i += 256)
            ((uint4*)wS16)[i] = ((const uint4*)Wr)[i];
    } else {
        for (int i = t; i < 64 * 32; i += 256)
            wS16[i] = f2bf(((const float*)Wr)[i]);
    }
    if (t < 32) Bs[t] = loadElem(bias, t, isb);

    // stage own h rows (raw bf16 copy)
    for (int i = t; i < 64 * 8; i += 256) {
        int nl = i >> 3, k0 = (i & 7) << 3;
        int gn = node0 + nl;
        uint4 u = make_uint4(0, 0, 0, 0);
        if (gn < N) u = *(const uint4*)(h + (size_t)gn * 64 + k0);
        *(uint2*)&hS16[nl * SH + k0]     = make_uint2(u.x, u.y);
        *(uint2*)&hS16[nl * SH + k0 + 4] = make_uint2(u.z, u.w);
    }

    // gather mean of y2 rows -> amB (8-lane groups, 2 nodes per group)
    {
        int g = t >> 3, l = t & 7;
        int gb = (t & 63) & ~7;
#pragma unroll
        for (int jj = 0; jj < 2; ++jj) {
            int nl = g + 32 * jj;
            int node = node0 + nl;
            float ax = 0.f, ay = 0.f, az = 0.f, aw = 0.f;
            float inv = 0.f;
            if (node < N) {
                int beg = rowptr[node], end = rowptr[node + 1];
                int d = end - beg;
                if (d > 0) {
                    inv = 1.0f / (float)d;
                    for (int bs = beg; bs < end; bs += 8) {
                        int cnt = min(end - bs, 8);
                        int idx = esorted[min(bs + l, end - 1)];
                        int dd = 0;
                        for (; dd + 4 <= cnt; dd += 4) {
                            int s0 = __shfl(idx, gb + dd + 0, 64);
                            int s1 = __shfl(idx, gb + dd + 1, 64);
                            int s2 = __shfl(idx, gb + dd + 2, 64);
                            int s3 = __shfl(idx, gb + dd + 3, 64);
                            ushort4 u0 = *(const ushort4*)(y2 + (size_t)s0 * 32 + 4 * l);
                            ushort4 u1 = *(const ushort4*)(y2 + (size_t)s1 * 32 + 4 * l);
                            ushort4 u2 = *(const ushort4*)(y2 + (size_t)s2 * 32 + 4 * l);
                            ushort4 u3 = *(const ushort4*)(y2 + (size_t)s3 * 32 + 4 * l);
                            ax += bf2f(u0.x) + bf2f(u1.x) + bf2f(u2.x) + bf2f(u3.x);
                            ay += bf2f(u0.y) + bf2f(u1.y) + bf2f(u2.y) + bf2f(u3.y);
                            az += bf2f(u0.z) + bf2f(u1.z) + bf2f(u2.z) + bf2f(u3.z);
                            aw += bf2f(u0.w) + bf2f(u1.w) + bf2f(u2.w) + bf2f(u3.w);
                        }
                        for (; dd < cnt; ++dd) {
                            int s = __shfl(idx, gb + dd, 64);
                            ushort4 u = *(const ushort4*)(y2 + (size_t)s * 32 + 4 * l);
                            ax += bf2f(u.x); ay += bf2f(u.y);
                            az += bf2f(u.z); aw += bf2f(u.w);
                        }
                    }
                }
            }
            *(float4*)&amB[nl * SAM + 4 * l] =
                make_float4(ax * inv, ay * inv, az * inv, aw * inv);
        }
    }
    __syncthreads();

    // GEMM: acc = own @ W2r; epilogue: + am + bias
    int cq = t % 8, nq = t / 8;                    // nq in [0,32), 2 nodes each
    float4 acc0 = make_float4(0.f, 0.f, 0.f, 0.f);
    float4 acc1 = make_float4(0.f, 0.f, 0.f, 0.f);

#pragma unroll 8
    for (int k = 0; k < 64; ++k) {
        uint2 wu = *(const uint2*)&wS16[k * 32 + 4 * cq];
        float4 w = make_float4(bflo(wu.x), bfhi(wu.x), bflo(wu.y), bfhi(wu.y));
        float a0 = bf2f(hS16[(2 * nq) * SH + k]);
        float a1 = bf2f(hS16[(2 * nq + 1) * SH + k]);
        fma4(acc0, a0, w);
        fma4(acc1, a1, w);
    }

    float4 bv = *(const float4*)&Bs[4 * cq];
#pragma unroll
    for (int j = 0; j < 2; ++j) {
        int nl = 2 * nq + j;
        int node = node0 + nl;
        if (node >= N) continue;
        float4 r = (j == 0) ? acc0 : acc1;
        float4 ap = *(const float4*)&amB[nl * SAM + 4 * cq];
        r.x += ap.x + bv.x; r.y += ap.y + bv.y;
        r.z += ap.z + bv.z; r.w += ap.w + bv.w;
        if (!isb) {
            *(float4*)((float*)outp + (size_t)node * 32 + 4 * cq) = r;
        } else {
            ushort4 o = { f2bf(r.x), f2bf(r.y), f2bf(r.z), f2bf(r.w) };
            *(ushort4*)((unsigned short*)outp + (size_t)node * 32 + 4 * cq) = o;
        }
    }
}

extern "C" void kernel_launch(void* const* d_in, const int* in_sizes, int n_in,
                              void* d_out, int out_size, void* d_ws, size_t ws_size,
                              hipStream_t stream) {
    const void* x   = d_in[0];
    const int*  ei  = (const int*)d_in[1];
    const void* W1l = d_in[2];
    const void* W1r = d_in[3];
    const void* b1  = d_in[4];
    const void* W2l = d_in[5];
    const void* W2r = d_in[6];
    const void* b2  = d_in[7];

    const int N = in_sizes[0] / 64;
    const int E = in_sizes[1] / 2;
    const int NBUK = (N + BN - 1) >> BSHIFT;              // 782 @ N=100k
    const int nblk = (E + CHUNK - 1) / CHUNK;             // 1172 @ E=1.2M

    // ws: flags | bukTot | bukOff | rowptr[N+1] | recs[E] | esorted[E] | xb | h
    // blockHist overlays xb (dead before k_cast); y2 overlays xb (dead after layer 1).
    char* base = (char*)d_ws;
    size_t off = 0;
    auto alloc = [&](size_t bytes) { size_t o = off; off = (off + bytes + 255) & ~(size_t)255; return o; };
    int* flags   = (int*)(base + alloc(256));
    int* bukTot  = (int*)(base + alloc((size_t)NBUK * 4));
    int* bukOff  = (int*)(base + alloc((size_t)(NBUK + 1) * 4));
    int* rowptr  = (int*)(base + alloc((size_t)(N + 1) * 4));
    unsigned int* recs = (unsigned int*)(base + alloc((size_t)E * 4));
    int* esorted = (int*)(base + alloc((size_t)E * 4));
    unsigned short* xb = (unsigned short*)(base + alloc((size_t)N * 64 * 2));
    unsigned short* h  = (unsigned short*)(base + alloc((size_t)N * 64 * 2));
    (void)ws_size;

    int* blockHist = (int*)xb;            // [NBUK][nblk] = 3.7 MB, dead before k_cast
    unsigned short* y2 = xb;              // [N,32] = 6.4 MB, xb dead after layer 1

    const int B = 256;
    int nd = 2 * E; if (nd > 2048) nd = 2048;

    k_detect<<<1, 256, 0, stream>>>(ei, nd, (const unsigned int*)x, 512, flags);
    k_bcount<<<nblk, B, 0, stream>>>(ei, flags, blockHist, E, NBUK, nblk);
    k_rowscan<<<NBUK, B, 0, stream>>>(blockHist, bukTot, nblk);
    k_toto<<<1, 1024, 0, stream>>>(bukTot, bukOff, rowptr, NBUK, E, N);
    k_part<<<nblk, B, 0, stream>>>(ei, flags, blockHist, bukOff, recs, E, NBUK, nblk);
    k_cast<<<(N * 8 + B - 1) / B, B, 0, stream>>>(x, xb, N * 8, flags);
    k_csr<<<NBUK, B, 0, stream>>>(recs, bukOff, rowptr, esorted, N);

    const int ntile = (N + 63) / 64;
    // layer 1: h = relu( mean_nbr(xb)@W1l + xb@W1r + b1 )
    k_fused<64, true, false><<<ntile, B, 0, stream>>>(xb, rowptr, esorted,
                                                      W1l, W1r, b1, h, N, flags);
    // layer 2, GEMM-first: y2 = h@W2l ; out = mean_nbr(y2) + h@W2r + b2
    k_gemm32<<<(N + 127) / 128, B, 0, stream>>>(h, W2l, y2, N, flags);
    k_fused2<<<ntile, B, 0, stream>>>(y2, h, rowptr, esorted, W2r, b2,
                                      d_out, N, flags);
}

// Round 13
// 233.933 us; speedup vs baseline: 1.0735x; 1.0735x over previous
//
#include <hip/hip_runtime.h>

// ---------- bf16 helpers (bit-level, RNE) ----------
__device__ __forceinline__ float bf2f(unsigned short u) {
    union { unsigned int i; float f; } v;
    v.i = ((unsigned int)u) << 16;
    return v.f;
}
__device__ __forceinline__ unsigned short f2bf(float f) {
    union { float f; unsigned int u; } v;
    v.f = f;
    unsigned int u = v.u;
    u += 0x7FFFu + ((u >> 16) & 1u);   // round-to-nearest-even
    return (unsigned short)(u >> 16);
}
__device__ __forceinline__ float loadElem(const void* p, size_t i, int isb) {
    return isb ? bf2f(((const unsigned short*)p)[i]) : ((const float*)p)[i];
}
__device__ __forceinline__ void fma4(float4& a, float s, const float4& w) {
    a.x += s * w.x; a.y += s * w.y; a.z += s * w.z; a.w += s * w.w;
}
__device__ __forceinline__ float bflo(unsigned int u) {
    union { unsigned int i; float f; } v; v.i = u << 16; return v.f;
}
__device__ __forceinline__ float bfhi(unsigned int u) {
    union { unsigned int i; float f; } v; v.i = u & 0xFFFF0000u; return v.f;
}

#define CHUNK 4096            // edges per partition block (r7/r9/r11 proven)
#define BSHIFT 8              // 256 nodes per sort bucket (r7/r11 proven)

// ---------- runtime dtype detection (proven r3-r12) ----------
__global__ void k_detect(const int* __restrict__ ei, int newords,
                         const unsigned int* __restrict__ xw, int nxw,
                         int* __restrict__ flags) {
    __shared__ int aOr;
    __shared__ int plaus;
    if (threadIdx.x == 0) { aOr = 0; plaus = 0; }
    __syncthreads();
    int v = 0;
    for (int i = 1 + 2 * (int)threadIdx.x; i < newords; i += 512) v |= ei[i];
    int pl = 0;
    for (int i = threadIdx.x; i < nxw; i += 256) {
        unsigned short lo = (unsigned short)(xw[i] & 0xFFFFu);
        float a = fabsf(bf2f(lo));
        if (a > 1e-5f && a < 100.0f) pl++;
    }
    atomicOr(&aOr, v);
    atomicAdd(&plaus, pl);
    __syncthreads();
    if (threadIdx.x == 0) {
        flags[0] = (aOr == 0) ? 1 : 0;
        flags[1] = (2 * plaus >= nxw) ? 1 : 0;
    }
}

// ---------- cast x -> bf16 (copy-through if already bf16) ----------
__global__ void k_cast(const void* __restrict__ x, unsigned short* __restrict__ xb,
                       int n8, const int* __restrict__ flags) {
    int i = blockIdx.x * blockDim.x + threadIdx.x;
    if (i >= n8) return;
    if (flags[1]) {
        ((uint4*)xb)[i] = ((const uint4*)x)[i];
    } else {
        const float4* xf = (const float4*)x;
        float4 a = xf[2 * i], b = xf[2 * i + 1];
        ushort4 lo = { f2bf(a.x), f2bf(a.y), f2bf(a.z), f2bf(a.w) };
        ushort4 hi = { f2bf(b.x), f2bf(b.y), f2bf(b.z), f2bf(b.w) };
        ((ushort4*)xb)[2 * i] = lo;
        ((ushort4*)xb)[2 * i + 1] = hi;
    }
}

// ---------- CSR build: counting sort with parallel scans (r11 verbatim) ----------
__global__ __launch_bounds__(256) void k_bcount(
        const int* __restrict__ ei, const int* __restrict__ flags,
        int* __restrict__ blockHist, int E, int NBUK, int nblk) {
    __shared__ int hist[512];
    int t = threadIdx.x;
    for (int i = t; i < NBUK; i += 256) hist[i] = 0;
    __syncthreads();
    int q = flags[0];
    int e0 = blockIdx.x * CHUNK, e1 = min(E, e0 + CHUNK);
    for (int e = e0 + t; e < e1; e += 256) {
        int dst = ei[((size_t)(E + e)) << q];
        atomicAdd(&hist[dst >> BSHIFT], 1);
    }
    __syncthreads();
    for (int i = t; i < NBUK; i += 256)
        blockHist[(size_t)i * nblk + blockIdx.x] = hist[i];
}

__global__ __launch_bounds__(256) void k_rowscan(
        int* __restrict__ blockHist, int* __restrict__ bukTot, int nblk) {
    __shared__ int sh[256];
    int t = threadIdx.x;
    int* row = blockHist + (size_t)blockIdx.x * nblk;
    int carry = 0;
    for (int base = 0; base < nblk; base += 256) {
        int i = base + t;
        int v = (i < nblk) ? row[i] : 0;
        sh[t] = v;
        __syncthreads();
        for (int off = 1; off < 256; off <<= 1) {
            int u = (t >= off) ? sh[t - off] : 0;
            __syncthreads();
            sh[t] += u;
            __syncthreads();
        }
        if (i < nblk) row[i] = carry + sh[t] - v;
        int tot = sh[255];
        __syncthreads();
        carry += tot;
    }
    if (t == 0) bukTot[blockIdx.x] = carry;
}

__global__ __launch_bounds__(512) void k_toto(
        const int* __restrict__ bukTot, int* __restrict__ bukOff,
        int* __restrict__ rowptr, int NBUK, int E, int N) {
    __shared__ int sh[512];
    int t = threadIdx.x;
    int v = (t < NBUK) ? bukTot[t] : 0;
    sh[t] = v;
    __syncthreads();
    for (int off = 1; off < 512; off <<= 1) {
        int u = (t >= off) ? sh[t - off] : 0;
        __syncthreads();
        sh[t] += u;
        __syncthreads();
    }
    if (t < NBUK) bukOff[t] = sh[t] - v;
    if (t == 0) { bukOff[NBUK] = E; rowptr[N] = E; }
}

__global__ __launch_bounds__(256) void k_part(
        const int* __restrict__ ei, const int* __restrict__ flags,
        const int* __restrict__ blockHist, const int* __restrict__ bukOff,
        unsigned int* __restrict__ recs, int E, int NBUK, int nblk) {
    __shared__ int cur[512];
    int t = threadIdx.x;
    for (int i = t; i < NBUK; i += 256)
        cur[i] = blockHist[(size_t)i * nblk + blockIdx.x] + bukOff[i];
    __syncthreads();
    int q = flags[0];
    int e0 = blockIdx.x * CHUNK, e1 = min(E, e0 + CHUNK);
    for (int e = e0 + t; e < e1; e += 256) {
        int dst = ei[((size_t)(E + e)) << q];
        int src = ei[((size_t)e) << q];
        int pos = atomicAdd(&cur[dst >> BSHIFT], 1);
        recs[pos] = ((unsigned int)src << BSHIFT) | (unsigned int)(dst & ((1 << BSHIFT) - 1));
    }
}

__global__ __launch_bounds__(256) void k_csr(
        const unsigned int* __restrict__ recs, const int* __restrict__ bukOff,
        int* __restrict__ rowptr, int* __restrict__ esorted, int N) {
    __shared__ int degLoc[256];
    __shared__ int offLoc[256];
    __shared__ int wcur[256];
    int t = threadIdx.x;
    int node0 = blockIdx.x << BSHIFT;
    int r0 = bukOff[blockIdx.x], r1 = bukOff[blockIdx.x + 1];
    degLoc[t] = 0;
    __syncthreads();
    for (int i = r0 + t; i < r1; i += 256)
        atomicAdd(&degLoc[recs[i] & 255], 1);
    __syncthreads();
    int v = degLoc[t];
    offLoc[t] = v;
    __syncthreads();
    for (int off = 1; off < 256; off <<= 1) {
        int u = (t >= off) ? offLoc[t - off] : 0;
        __syncthreads();
        offLoc[t] += u;
        __syncthreads();
    }
    int excl = offLoc[t] - v;
    int node = node0 + t;
    if (node < N) rowptr[node] = r0 + excl;
    wcur[t] = r0 + excl;
    __syncthreads();
    for (int i = r0 + t; i < r1; i += 256) {
        unsigned int rec = recs[i];
        int pos = atomicAdd(&wcur[rec & 255], 1);
        esorted[pos] = (int)(rec >> BSHIFT);
    }
}

// ---------- fused layer (r11 structure; ONLY change: gather ILP 4 -> 8) ----------
// One block = 64 nodes, 256 threads. Phase 1: 16-lane-group register gather ->
// amBuf (f32), 8 rows in flight. Phase 2: acc = am @ Wl (bf16 weights in LDS).
// Restage (own rows; Wr). Phase 3: acc += own @ Wr. Epilogue +bias (+relu).
template<int CHOUT, bool RELU, bool FINAL>
__global__ __launch_bounds__(256) void k_fused(
        const unsigned short* __restrict__ feat,   // [N,64] bf16: xb (L1) or h (L2)
        const int* __restrict__ rowptr,
        const int* __restrict__ esorted,
        const void* __restrict__ Wl,               // [64,CHOUT]
        const void* __restrict__ Wr,               // [64,CHOUT]
        const void* __restrict__ bias,             // [CHOUT]
        void* __restrict__ outp,                   // [N,CHOUT]
        int N, const int* __restrict__ flags) {
    constexpr int SA = 68;                         // f32 stride, 16B-aligned float4
    __shared__ float amBuf[64 * SA];
    __shared__ unsigned short wS16[64 * CHOUT];
    __shared__ float Bs[CHOUT];

    int t = threadIdx.x;
    int isb = flags[1];
    int node0 = blockIdx.x << 6;

    if (isb) {
        for (int i = t; i < (64 * CHOUT) / 8; i += 256)
            ((uint4*)wS16)[i] = ((const uint4*)Wl)[i];
    } else {
        for (int i = t; i < 64 * CHOUT; i += 256)
            wS16[i] = f2bf(((const float*)Wl)[i]);
    }
    if (t < CHOUT) Bs[t] = loadElem(bias, t, isb);

    // ---- phase 1: gather mean of neighbor rows -> amBuf[nl][k], 8-row ILP ----
    {
        int g = t >> 4, l = t & 15;
        int gb = (t & 63) & ~15;                   // group base lane within wave
#pragma unroll
        for (int jj = 0; jj < 4; ++jj) {
            int nl = g + 16 * jj;
            int node = node0 + nl;
            float ax = 0.f, ay = 0.f, az = 0.f, aw = 0.f;
            float inv = 0.f;
            if (node < N) {
                int beg = rowptr[node], end = rowptr[node + 1];
                int d = end - beg;
                if (d > 0) {
                    inv = 1.0f / (float)d;
                    for (int bs = beg; bs < end; bs += 16) {
                        int cnt = min(end - bs, 16);
                        int idx = esorted[min(bs + l, end - 1)];
                        int dd = 0;
                        for (; dd + 8 <= cnt; dd += 8) {      // 8 rows in flight
                            int s0 = __shfl(idx, gb + dd + 0, 64);
                            int s1 = __shfl(idx, gb + dd + 1, 64);
                            int s2 = __shfl(idx, gb + dd + 2, 64);
                            int s3 = __shfl(idx, gb + dd + 3, 64);
                            int s4 = __shfl(idx, gb + dd + 4, 64);
                            int s5 = __shfl(idx, gb + dd + 5, 64);
                            int s6 = __shfl(idx, gb + dd + 6, 64);
                            int s7 = __shfl(idx, gb + dd + 7, 64);
                            ushort4 u0 = *(const ushort4*)(feat + (size_t)s0 * 64 + 4 * l);
                            ushort4 u1 = *(const ushort4*)(feat + (size_t)s1 * 64 + 4 * l);
                            ushort4 u2 = *(const ushort4*)(feat + (size_t)s2 * 64 + 4 * l);
                            ushort4 u3 = *(const ushort4*)(feat + (size_t)s3 * 64 + 4 * l);
                            ushort4 u4 = *(const ushort4*)(feat + (size_t)s4 * 64 + 4 * l);
                            ushort4 u5 = *(const ushort4*)(feat + (size_t)s5 * 64 + 4 * l);
                            ushort4 u6 = *(const ushort4*)(feat + (size_t)s6 * 64 + 4 * l);
                            ushort4 u7 = *(const ushort4*)(feat + (size_t)s7 * 64 + 4 * l);
                            ax += bf2f(u0.x) + bf2f(u1.x) + bf2f(u2.x) + bf2f(u3.x)
                                + bf2f(u4.x) + bf2f(u5.x) + bf2f(u6.x) + bf2f(u7.x);
                            ay += bf2f(u0.y) + bf2f(u1.y) + bf2f(u2.y) + bf2f(u3.y)
                                + bf2f(u4.y) + bf2f(u5.y) + bf2f(u6.y) + bf2f(u7.y);
                            az += bf2f(u0.z) + bf2f(u1.z) + bf2f(u2.z) + bf2f(u3.z)
                                + bf2f(u4.z) + bf2f(u5.z) + bf2f(u6.z) + bf2f(u7.z);
                            aw += bf2f(u0.w) + bf2f(u1.w) + bf2f(u2.w) + bf2f(u3.w)
                                + bf2f(u4.w) + bf2f(u5.w) + bf2f(u6.w) + bf2f(u7.w);
                        }
                        for (; dd + 4 <= cnt; dd += 4) {
                            int s0 = __shfl(idx, gb + dd + 0, 64);
                            int s1 = __shfl(idx, gb + dd + 1, 64);
                            int s2 = __shfl(idx, gb + dd + 2, 64);
                            int s3 = __shfl(idx, gb + dd + 3, 64);
                            ushort4 u0 = *(const ushort4*)(feat + (size_t)s0 * 64 + 4 * l);
                            ushort4 u1 = *(const ushort4*)(feat + (size_t)s1 * 64 + 4 * l);
                            ushort4 u2 = *(const ushort4*)(feat + (size_t)s2 * 64 + 4 * l);
                            ushort4 u3 = *(const ushort4*)(feat + (size_t)s3 * 64 + 4 * l);
                            ax += bf2f(u0.x) + bf2f(u1.x) + bf2f(u2.x) + bf2f(u3.x);
                            ay += bf2f(u0.y) + bf2f(u1.y) + bf2f(u2.y) + bf2f(u3.y);
                            az += bf2f(u0.z) + bf2f(u1.z) + bf2f(u2.z) + bf2f(u3.z);
                            aw += bf2f(u0.w) + bf2f(u1.w) + bf2f(u2.w) + bf2f(u3.w);
                        }
                        for (; dd < cnt; ++dd) {
                            int s = __shfl(idx, gb + dd, 64);
                            ushort4 u = *(const ushort4*)(feat + (size_t)s * 64 + 4 * l);
                            ax += bf2f(u.x); ay += bf2f(u.y);
                            az += bf2f(u.z); aw += bf2f(u.w);
                        }
                    }
                }
            }
            *(float4*)&amBuf[nl * SA + 4 * l] =
                make_float4(ax * inv, ay * inv, az * inv, aw * inv);
        }
    }
    __syncthreads();

    // ---- phase 2: acc = am @ Wl ----
    constexpr int CQ = CHOUT / 4;                  // 16 or 8
    constexpr int NPT = CHOUT / 16;                // 4 or 2 nodes per thread
    int cq = t % CQ, nq = t / CQ;
    float4 acc[NPT];
#pragma unroll
    for (int j = 0; j < NPT; ++j) acc[j] = make_float4(0.f, 0.f, 0.f, 0.f);

#pragma unroll 8
    for (int k = 0; k < 64; ++k) {
        uint2 wu = *(const uint2*)&wS16[k * CHOUT + 4 * cq];
        float4 w = make_float4(bflo(wu.x), bfhi(wu.x), bflo(wu.y), bfhi(wu.y));
#pragma unroll
        for (int j = 0; j < NPT; ++j)
            fma4(acc[j], amBuf[(nq * NPT + j) * SA + k], w);
    }
    __syncthreads();

    // ---- restage: own rows -> amBuf, Wr -> wS16 ----
    for (int i = t; i < 64 * 8; i += 256) {
        int nl = i >> 3, k0 = (i & 7) << 3;
        int gn = node0 + nl;
        float v[8];
        if (gn < N) {
            uint4 u = *(const uint4*)(feat + (size_t)gn * 64 + k0);
            v[0] = bflo(u.x); v[1] = bfhi(u.x);
            v[2] = bflo(u.y); v[3] = bfhi(u.y);
            v[4] = bflo(u.z); v[5] = bfhi(u.z);
            v[6] = bflo(u.w); v[7] = bfhi(u.w);
        } else {
#pragma unroll
            for (int j = 0; j < 8; ++j) v[j] = 0.f;
        }
#pragma unroll
        for (int j = 0; j < 8; ++j) amBuf[nl * SA + k0 + j] = v[j];
    }
    if (isb) {
        for (int i = t; i < (64 * CHOUT) / 8; i += 256)
            ((uint4*)wS16)[i] = ((const uint4*)Wr)[i];
    } else {
        for (int i = t; i < 64 * CHOUT; i += 256)
            wS16[i] = f2bf(((const float*)Wr)[i]);
    }
    __syncthreads();

    // ---- phase 3: acc += own @ Wr ----
#pragma unroll 8
    for (int k = 0; k < 64; ++k) {
        uint2 wu = *(const uint2*)&wS16[k * CHOUT + 4 * cq];
        float4 w = make_float4(bflo(wu.x), bfhi(wu.x), bflo(wu.y), bfhi(wu.y));
#pragma unroll
        for (int j = 0; j < NPT; ++j)
            fma4(acc[j], amBuf[(nq * NPT + j) * SA + k], w);
    }

    // ---- epilogue ----
    float4 bv = *(const float4*)&Bs[4 * cq];
#pragma unroll
    for (int j = 0; j < NPT; ++j) {
        int nl = nq * NPT + j;
        int node = node0 + nl;
        if (node >= N) continue;
        float4 r = acc[j];
        r.x += bv.x; r.y += bv.y; r.z += bv.z; r.w += bv.w;
        if (RELU) {
            r.x = fmaxf(r.x, 0.f); r.y = fmaxf(r.y, 0.f);
            r.z = fmaxf(r.z, 0.f); r.w = fmaxf(r.w, 0.f);
        }
        if (FINAL && !isb) {
            *(float4*)((float*)outp + (size_t)node * CHOUT + 4 * cq) = r;
        } else {
            ushort4 o = { f2bf(r.x), f2bf(r.y), f2bf(r.z), f2bf(r.w) };
            *(ushort4*)((unsigned short*)outp + (size_t)node * CHOUT + 4 * cq) = o;
        }
    }
}

extern "C" void kernel_launch(void* const* d_in, const int* in_sizes, int n_in,
                              void* d_out, int out_size, void* d_ws, size_t ws_size,
                              hipStream_t stream) {
    const void* x   = d_in[0];
    const int*  ei  = (const int*)d_in[1];
    const void* W1l = d_in[2];
    const void* W1r = d_in[3];
    const void* b1  = d_in[4];
    const void* W2l = d_in[5];
    const void* W2r = d_in[6];
    const void* b2  = d_in[7];

    const int N = in_sizes[0] / 64;
    const int E = in_sizes[1] / 2;
    const int NBUK = (N + (1 << BSHIFT) - 1) >> BSHIFT;   // 391 @ N=100k (<= 512)
    const int nblk = (E + CHUNK - 1) / CHUNK;             // 293 @ E=1.2M

    // ws: flags | bukTot | bukOff | rowptr[N+1] | recs[E] | esorted[E] | xb | h
    // blockHist overlays xb (dead before k_cast writes xb).
    char* base = (char*)d_ws;
    size_t off = 0;
    auto alloc = [&](size_t bytes) { size_t o = off; off = (off + bytes + 255) & ~(size_t)255; return o; };
    int* flags   = (int*)(base + alloc(256));
    int* bukTot  = (int*)(base + alloc((size_t)NBUK * 4));
    int* bukOff  = (int*)(base + alloc((size_t)(NBUK + 1) * 4));
    int* rowptr  = (int*)(base + alloc((size_t)(N + 1) * 4));
    unsigned int* recs = (unsigned int*)(base + alloc((size_t)E * 4));
    int* esorted = (int*)(base + alloc((size_t)E * 4));
    unsigned short* xb = (unsigned short*)(base + alloc((size_t)N * 64 * 2));
    unsigned short* h  = (unsigned short*)(base + alloc((size_t)N * 64 * 2));
    (void)ws_size;

    int* blockHist = (int*)xb;     // [NBUK][nblk], dead after k_part

    const int B = 256;
    int nd = 2 * E; if (nd > 2048) nd = 2048;

    k_detect<<<1, 256, 0, stream>>>(ei, nd, (const unsigned int*)x, 512, flags);
    k_bcount<<<nblk, B, 0, stream>>>(ei, flags, blockHist, E, NBUK, nblk);
    k_rowscan<<<NBUK, B, 0, stream>>>(blockHist, bukTot, nblk);
    k_toto<<<1, 512, 0, stream>>>(bukTot, bukOff, rowptr, NBUK, E, N);
    k_part<<<nblk, B, 0, stream>>>(ei, flags, blockHist, bukOff, recs, E, NBUK, nblk);
    k_cast<<<(N * 8 + B - 1) / B, B, 0, stream>>>(x, xb, N * 8, flags);
    k_csr<<<NBUK, B, 0, stream>>>(recs, bukOff, rowptr, esorted, N);

    const int ntile = (N + 63) / 64;
    // h = relu( mean_nbr(xb)@W1l + xb@W1r + b1 )
    k_fused<64, true, false><<<ntile, B, 0, stream>>>(xb, rowptr, esorted,
                                                      W1l, W1r, b1, h, N, flags);
    // out = mean_nbr(h)@W2l + h@W2r + b2
    k_fused<32, false, true><<<ntile, B, 0, stream>>>(h, rowptr, esorted,
                                                      W2l, W2r, b2, d_out, N, flags);
}